// Round 1
// baseline (1564.307 us; speedup 1.0000x reference)
//
#include <hip/hip_runtime.h>

#define LL 2048
#define HH 2048
#define EE 4096
#define NS 16
#define RR 128

typedef __bf16 bf16x8 __attribute__((ext_vector_type(8)));
typedef float f32x4 __attribute__((ext_vector_type(4)));

__device__ __forceinline__ unsigned short f2bf(float f) {
  union { float f; unsigned int u; } v; v.f = f;
  unsigned int r = v.u + 0x7fffu + ((v.u >> 16) & 1u);
  return (unsigned short)(r >> 16);
}

// ---------------- fp32 -> bf16 cast (vectorized x4) ----------------
__global__ void cast_bf16_k(const float* __restrict__ in,
                            unsigned short* __restrict__ out, int n4) {
  int i = blockIdx.x * blockDim.x + threadIdx.x;
  if (i >= n4) return;
  float4 v = reinterpret_cast<const float4*>(in)[i];
  ushort4 o;
  o.x = f2bf(v.x); o.y = f2bf(v.y); o.z = f2bf(v.z); o.w = f2bf(v.w);
  reinterpret_cast<ushort4*>(out)[i] = o;
}

// ---------------- bf16 BT-GEMM: C[M,N] = A[M,K] * B[N,K]^T ----------------
// block = 256 threads = 4 waves; block tile 64(M) x 128(N); wave tile 32x64.
// mfma_f32_16x16x32_bf16, verified layouts:
//   A frag: m = lane&15, k = (lane>>4)*8 + j   (8 contiguous bf16 -> 16B load)
//   B frag: n = lane&15, k = (lane>>4)*8 + j
//   C/D:    col = lane&15, row = (lane>>4)*4 + reg
__global__ __launch_bounds__(256) void gemm_bt(
    const unsigned short* __restrict__ A,
    const unsigned short* __restrict__ B,
    float* __restrict__ C,
    int M, int N, int K, int tilesN) {
  // supertile swizzle: 8 M-tiles per group for B reuse in L2
  int bid = blockIdx.x;
  int groupSize = 8 * tilesN;
  int g = bid / groupSize, r = bid % groupSize;
  int tm = g * 8 + (r & 7);
  int tn = r >> 3;

  int tid = threadIdx.x;
  int wave = tid >> 6, lane = tid & 63;
  int wm = wave & 1, wn = wave >> 1;
  int m16 = lane & 15, quad = lane >> 4;
  int rowBase = tm * 64 + wm * 32;
  int colBase = tn * 128 + wn * 64;

  const unsigned short* a0p = A + (size_t)(rowBase + m16) * K + quad * 8;
  const unsigned short* a1p = A + (size_t)(rowBase + 16 + m16) * K + quad * 8;
  const unsigned short* bp[4];
  bool bok[4];
#pragma unroll
  for (int j = 0; j < 4; ++j) {
    int col = colBase + j * 16 + m16;
    bok[j] = (col < N);
    bp[j] = B + (size_t)(bok[j] ? col : 0) * K + quad * 8;
  }

  f32x4 acc[2][4];
#pragma unroll
  for (int i = 0; i < 2; ++i)
#pragma unroll
    for (int j = 0; j < 4; ++j)
#pragma unroll
      for (int t = 0; t < 4; ++t) acc[i][j][t] = 0.0f;

  bf16x8 zero8;
#pragma unroll
  for (int t = 0; t < 8; ++t) zero8[t] = (__bf16)0.0f;

  for (int k = 0; k < K; k += 32) {
    bf16x8 a0 = *reinterpret_cast<const bf16x8*>(a0p + k);
    bf16x8 a1 = *reinterpret_cast<const bf16x8*>(a1p + k);
    bf16x8 b[4];
#pragma unroll
    for (int j = 0; j < 4; ++j)
      b[j] = bok[j] ? *reinterpret_cast<const bf16x8*>(bp[j] + k) : zero8;
#pragma unroll
    for (int j = 0; j < 4; ++j) {
      acc[0][j] = __builtin_amdgcn_mfma_f32_16x16x32_bf16(a0, b[j], acc[0][j], 0, 0, 0);
      acc[1][j] = __builtin_amdgcn_mfma_f32_16x16x32_bf16(a1, b[j], acc[1][j], 0, 0, 0);
    }
  }

#pragma unroll
  for (int i = 0; i < 2; ++i)
#pragma unroll
    for (int j = 0; j < 4; ++j) {
      int col = colBase + j * 16 + m16;
      if (col >= N) continue;
      int row0 = rowBase + i * 16 + quad * 4;
#pragma unroll
      for (int t = 0; t < 4; ++t)
        C[(size_t)(row0 + t) * N + col] = acc[i][j][t];
    }
}

// ---------------- depthwise causal conv (K=4) + bias + silu ----------------
__global__ __launch_bounds__(256) void conv_silu_k(
    const float* __restrict__ proj, const float* __restrict__ cw,
    const float* __restrict__ cb, float* __restrict__ hf,
    unsigned short* __restrict__ hb) {
  int e = blockIdx.x * 256 + threadIdx.x;
  int l = blockIdx.y;
  float acc = cb[e];
#pragma unroll
  for (int k = 0; k < 4; ++k) {
    int lt = l - 3 + k;
    if (lt >= 0) acc += cw[e * 4 + k] * proj[(size_t)lt * (2 * EE) + e];
  }
  float s = acc / (1.0f + __expf(-acc));
  hf[(size_t)l * EE + e] = s;
  hb[(size_t)l * EE + e] = f2bf(s);
}

// ---------------- extract dt rows of ssm -> bf16 [L,128] ----------------
__global__ void dtcast_k(const float* __restrict__ ssm,
                         unsigned short* __restrict__ dtin, int n) {
  int i = blockIdx.x * blockDim.x + threadIdx.x;
  if (i >= n) return;
  int l = i >> 7, r = i & 127;
  dtin[i] = f2bf(ssm[l * 160 + r]);
}

// ---------------- bias + softplus, in place on dt_raw [L,E] ----------------
__global__ void softplus_k(float* __restrict__ dt, const float* __restrict__ db,
                           int n) {
  int i = blockIdx.x * blockDim.x + threadIdx.x;
  if (i >= n) return;
  float x = dt[i] + db[i & (EE - 1)];
  dt[i] = (x > 20.0f) ? x : log1pf(__expf(x));
}

// ---------------- selective scan ----------------
// block = 256 threads = 16 e-channels x 16 states; one block per 16 e's.
// lane layout: n = tid&15 (state), e_local = tid>>4. Reduce over n via shfl_xor.
__global__ __launch_bounds__(256) void scan_k(
    const float* __restrict__ dt, const float* __restrict__ h,
    const float* __restrict__ ssm, const float* __restrict__ A_log,
    const float* __restrict__ Dp, const float* __restrict__ proj,
    unsigned short* __restrict__ yb) {
  int tid = threadIdx.x;
  int n = tid & 15, el = tid >> 4;
  int e = blockIdx.x * 16 + el;
  float A = -__expf(A_log[e * NS + n] * 1.44269504f) ; // exp(x) = 2^(x*log2e)
  float Dv = Dp[e];
  float s = 0.0f;
  // prefetch l=0
  float dtv = dt[e];
  float hv = h[e];
  float Bv = ssm[128 + n];
  float Cv = ssm[144 + n];
  float gv = proj[EE + e];
  for (int l = 0; l < LL; ++l) {
    float dt2 = 0.f, h2 = 0.f, B2 = 0.f, C2 = 0.f, g2 = 0.f;
    if (l + 1 < LL) {
      size_t o = (size_t)(l + 1) * EE + e;
      dt2 = dt[o];
      h2 = h[o];
      B2 = ssm[(l + 1) * 160 + 128 + n];
      C2 = ssm[(l + 1) * 160 + 144 + n];
      g2 = proj[(size_t)(l + 1) * 2 * EE + EE + e];
    }
    float dA = __expf(dtv * A);
    s = s * dA + dtv * hv * Bv;
    float part = s * Cv;
    part += __shfl_xor(part, 1);
    part += __shfl_xor(part, 2);
    part += __shfl_xor(part, 4);
    part += __shfl_xor(part, 8);
    if (n == 0) {
      float yv = (part + hv * Dv) * (gv / (1.0f + __expf(-gv)));
      yb[(size_t)l * EE + e] = f2bf(yv);
    }
    dtv = dt2; hv = h2; Bv = B2; Cv = C2; gv = g2;
  }
}

extern "C" void kernel_launch(void* const* d_in, const int* in_sizes, int n_in,
                              void* d_out, int out_size, void* d_ws, size_t ws_size,
                              hipStream_t stream) {
  const float* hs   = (const float*)d_in[0];
  const float* w1   = (const float*)d_in[1];
  const float* cw   = (const float*)d_in[2];
  const float* cb   = (const float*)d_in[3];
  const float* xw   = (const float*)d_in[4];
  const float* dtw  = (const float*)d_in[5];
  const float* dtb  = (const float*)d_in[6];
  const float* Alog = (const float*)d_in[7];
  const float* Dp   = (const float*)d_in[8];
  const float* ow   = (const float*)d_in[9];
  float* out = (float*)d_out;

  char* ws = (char*)d_ws;
  size_t off = 0;
  auto alloc = [&](size_t b) {
    char* p = ws + off;
    off += (b + 255) & ~(size_t)255;
    return p;
  };
  float* proj = (float*)alloc((size_t)LL * 2 * EE * 4);        // 67 MB
  float* hf   = (float*)alloc((size_t)LL * EE * 4);            // 33.5 MB
  unsigned short* hb = (unsigned short*)alloc((size_t)LL * EE * 2); // 16.8 MB
  float* dtf  = (float*)alloc((size_t)LL * EE * 4);            // 33.5 MB (shared w/ w1b)
  unsigned short* w1b = (unsigned short*)dtf; // w1 bf16 (used only before dtf is written)
  unsigned short* hsb = (unsigned short*)alloc((size_t)LL * HH * 2);   // 8.4 MB
  unsigned short* yb  = (unsigned short*)alloc((size_t)LL * EE * 2);   // 16.8 MB
  unsigned short* owb = (unsigned short*)alloc((size_t)HH * EE * 2);   // 16.8 MB
  unsigned short* xwb = (unsigned short*)alloc((size_t)160 * EE * 2);  // 1.3 MB
  float* ssm = (float*)alloc((size_t)LL * 160 * 4);                    // 1.3 MB
  unsigned short* dtin = (unsigned short*)alloc((size_t)LL * RR * 2);  // 0.5 MB
  unsigned short* dtwb = (unsigned short*)alloc((size_t)EE * RR * 2);  // 1.0 MB

  auto cast = [&](const float* in, unsigned short* o, int nelem) {
    int n4 = nelem / 4;
    cast_bf16_k<<<(n4 + 255) / 256, 256, 0, stream>>>(in, o, n4);
  };
  cast(hs, hsb, LL * HH);
  cast(w1, w1b, 2 * EE * HH);
  cast(xw, xwb, 160 * EE);
  cast(dtw, dtwb, EE * RR);
  cast(ow, owb, HH * EE);

  auto gemm = [&](const unsigned short* A, const unsigned short* Bm, float* Cm,
                  int M, int N, int K) {
    int tilesN = (N + 127) / 128;
    int tilesM = M / 64;  // M = 2048 always -> 32 tiles, divisible by 8
    gemm_bt<<<tilesM * tilesN, 256, 0, stream>>>(A, Bm, Cm, M, N, K, tilesN);
  };

  // 1) proj = hs @ in_proj_w^T   [2048, 8192]
  gemm(hsb, w1b, proj, LL, 2 * EE, HH);
  // 2) causal depthwise conv + silu -> h (f32 + bf16)
  conv_silu_k<<<dim3(EE / 256, LL), 256, 0, stream>>>(proj, cw, cb, hf, hb);
  // 3) ssm = h @ x_proj_w^T   [2048, 160]
  gemm(hb, xwb, ssm, LL, 160, EE);
  // 4) dt input slice -> bf16
  dtcast_k<<<(LL * RR + 255) / 256, 256, 0, stream>>>(ssm, dtin, LL * RR);
  // 5) dt_raw = dtin @ dt_proj_w^T   [2048, 4096]
  gemm(dtin, dtwb, dtf, LL, EE, RR);
  // 6) dt = softplus(dt_raw + b)
  softplus_k<<<(LL * EE + 255) / 256, 256, 0, stream>>>(dtf, dtb, LL * EE);
  // 7) selective scan + gating -> y (bf16)
  scan_k<<<EE / 16, 256, 0, stream>>>(dtf, hf, ssm, Alog, Dp, proj, yb);
  // 8) out = y @ out_proj_w^T   [2048, 2048]
  gemm(yb, owb, out, LL, HH, EE);
}

// Round 2
// 1105.414 us; speedup vs baseline: 1.4151x; 1.4151x over previous
//
#include <hip/hip_runtime.h>

#define LL 2048
#define HH 2048
#define EE 4096
#define NS 16
#define RR 128
#define CT 32            // chunk timesteps
#define NC (LL / CT)     // 64 chunks

typedef __bf16 bf16x8 __attribute__((ext_vector_type(8)));
typedef float f32x4 __attribute__((ext_vector_type(4)));

__device__ __forceinline__ unsigned short f2bf(float f) {
  union { float f; unsigned int u; } v; v.f = f;
  unsigned int r = v.u + 0x7fffu + ((v.u >> 16) & 1u);
  return (unsigned short)(r >> 16);
}

// ---------------- fp32 -> bf16 cast (vectorized x4) ----------------
__global__ void cast_bf16_k(const float* __restrict__ in,
                            unsigned short* __restrict__ out, int n4) {
  int i = blockIdx.x * blockDim.x + threadIdx.x;
  if (i >= n4) return;
  float4 v = reinterpret_cast<const float4*>(in)[i];
  ushort4 o;
  o.x = f2bf(v.x); o.y = f2bf(v.y); o.z = f2bf(v.z); o.w = f2bf(v.w);
  reinterpret_cast<ushort4*>(out)[i] = o;
}

// ---------------- bf16 BT-GEMM: C[M,N] = A[M,K] * B[N,K]^T ----------------
__global__ __launch_bounds__(256) void gemm_bt(
    const unsigned short* __restrict__ A,
    const unsigned short* __restrict__ B,
    float* __restrict__ C,
    int M, int N, int K, int tilesN) {
  int bid = blockIdx.x;
  int groupSize = 8 * tilesN;
  int g = bid / groupSize, r = bid % groupSize;
  int tm = g * 8 + (r & 7);
  int tn = r >> 3;

  int tid = threadIdx.x;
  int wave = tid >> 6, lane = tid & 63;
  int wm = wave & 1, wn = wave >> 1;
  int m16 = lane & 15, quad = lane >> 4;
  int rowBase = tm * 64 + wm * 32;
  int colBase = tn * 128 + wn * 64;

  const unsigned short* a0p = A + (size_t)(rowBase + m16) * K + quad * 8;
  const unsigned short* a1p = A + (size_t)(rowBase + 16 + m16) * K + quad * 8;
  const unsigned short* bp[4];
  bool bok[4];
#pragma unroll
  for (int j = 0; j < 4; ++j) {
    int col = colBase + j * 16 + m16;
    bok[j] = (col < N);
    bp[j] = B + (size_t)(bok[j] ? col : 0) * K + quad * 8;
  }

  f32x4 acc[2][4];
#pragma unroll
  for (int i = 0; i < 2; ++i)
#pragma unroll
    for (int j = 0; j < 4; ++j)
#pragma unroll
      for (int t = 0; t < 4; ++t) acc[i][j][t] = 0.0f;

  bf16x8 zero8;
#pragma unroll
  for (int t = 0; t < 8; ++t) zero8[t] = (__bf16)0.0f;

  for (int k = 0; k < K; k += 32) {
    bf16x8 a0 = *reinterpret_cast<const bf16x8*>(a0p + k);
    bf16x8 a1 = *reinterpret_cast<const bf16x8*>(a1p + k);
    bf16x8 b[4];
#pragma unroll
    for (int j = 0; j < 4; ++j)
      b[j] = bok[j] ? *reinterpret_cast<const bf16x8*>(bp[j] + k) : zero8;
#pragma unroll
    for (int j = 0; j < 4; ++j) {
      acc[0][j] = __builtin_amdgcn_mfma_f32_16x16x32_bf16(a0, b[j], acc[0][j], 0, 0, 0);
      acc[1][j] = __builtin_amdgcn_mfma_f32_16x16x32_bf16(a1, b[j], acc[1][j], 0, 0, 0);
    }
  }

#pragma unroll
  for (int i = 0; i < 2; ++i)
#pragma unroll
    for (int j = 0; j < 4; ++j) {
      int col = colBase + j * 16 + m16;
      if (col >= N) continue;
      int row0 = rowBase + i * 16 + quad * 4;
#pragma unroll
      for (int t = 0; t < 4; ++t)
        C[(size_t)(row0 + t) * N + col] = acc[i][j][t];
    }
}

// ---------------- depthwise causal conv (K=4) + bias + silu ----------------
__global__ __launch_bounds__(256) void conv_silu_k(
    const float* __restrict__ proj, const float* __restrict__ cw,
    const float* __restrict__ cb, float* __restrict__ hf,
    unsigned short* __restrict__ hb) {
  int e = blockIdx.x * 256 + threadIdx.x;
  int l = blockIdx.y;
  float acc = cb[e];
#pragma unroll
  for (int k = 0; k < 4; ++k) {
    int lt = l - 3 + k;
    if (lt >= 0) acc += cw[e * 4 + k] * proj[(size_t)lt * (2 * EE) + e];
  }
  float s = acc / (1.0f + __expf(-acc));
  hf[(size_t)l * EE + e] = s;
  hb[(size_t)l * EE + e] = f2bf(s);
}

// ---------------- extract dt rows of ssm -> bf16 [L,128] ----------------
__global__ void dtcast_k(const float* __restrict__ ssm,
                         unsigned short* __restrict__ dtin, int n) {
  int i = blockIdx.x * blockDim.x + threadIdx.x;
  if (i >= n) return;
  int l = i >> 7, r = i & 127;
  dtin[i] = f2bf(ssm[l * 160 + r]);
}

// ---------------- bias + softplus, in place on dt_raw [L,E] ----------------
__global__ void softplus_k(float* __restrict__ dt, const float* __restrict__ db,
                           int n) {
  int i = blockIdx.x * blockDim.x + threadIdx.x;
  if (i >= n) return;
  float x = dt[i] + db[i & (EE - 1)];
  dt[i] = (x > 20.0f) ? x : log1pf(__expf(x));
}

// ================= chunked selective scan =================
// Layout: thread (n = tid&15, el = tid>>4); block = (chunk c, e-group of 16).

// Pass A: local scan from s=0 over CT steps; emit P = prod(dA), S = final state.
__global__ __launch_bounds__(256) void scan_partA(
    const float* __restrict__ dt, const float* __restrict__ h,
    const float* __restrict__ ssm, const float* __restrict__ A_log,
    float* __restrict__ P, float* __restrict__ S) {
  int tid = threadIdx.x;
  int n = tid & 15, el = tid >> 4;
  int c = blockIdx.x, eg = blockIdx.y;
  int e = eg * 16 + el;
  float A = -__expf(A_log[e * NS + n]);
  float s = 0.0f, p = 1.0f;
  int l0 = c * CT;
#pragma unroll 4
  for (int t = 0; t < CT; ++t) {
    int l = l0 + t;
    size_t o = (size_t)l * EE + e;
    float dtv = dt[o];
    float hv = h[o];
    float Bv = ssm[l * 160 + 128 + n];
    float dA = __expf(dtv * A);
    s = s * dA + dtv * hv * Bv;
    p *= dA;
  }
  size_t idx = ((size_t)c * EE + e) * NS + n;
  P[idx] = p;
  S[idx] = s;
}

// Pass B: inter-chunk prefix scan over NC chunks, in place: S[c] <- s_init[c].
__global__ __launch_bounds__(256) void scan_chunkB(
    const float* __restrict__ P, float* __restrict__ S) {
  int gidx = blockIdx.x * 256 + threadIdx.x;  // [0, EE*NS)
  float s = 0.0f;
  float pv = P[gidx], sv = S[gidx];
  for (int c = 0; c < NC; ++c) {
    float pn = 0.0f, sn = 0.0f;
    if (c + 1 < NC) {
      size_t i2 = (size_t)(c + 1) * (EE * NS) + gidx;
      pn = P[i2];
      sn = S[i2];
    }
    float s_next = s * pv + sv;
    S[(size_t)c * (EE * NS) + gidx] = s;  // overwrite with incoming state
    s = s_next;
    pv = pn; sv = sn;
  }
}

// Pass C: rescan seeded with s_init; y = sum_n(s*C) + h*D, gated silu, bf16 out.
__global__ __launch_bounds__(256) void scan_partC(
    const float* __restrict__ dt, const float* __restrict__ h,
    const float* __restrict__ ssm, const float* __restrict__ A_log,
    const float* __restrict__ Dp, const float* __restrict__ proj,
    const float* __restrict__ Sinit, unsigned short* __restrict__ yb) {
  int tid = threadIdx.x;
  int n = tid & 15, el = tid >> 4;
  int c = blockIdx.x, eg = blockIdx.y;
  int e = eg * 16 + el;
  float A = -__expf(A_log[e * NS + n]);
  float Dv = Dp[e];
  float s = Sinit[((size_t)c * EE + e) * NS + n];
  int l0 = c * CT;
#pragma unroll 2
  for (int t = 0; t < CT; ++t) {
    int l = l0 + t;
    size_t o = (size_t)l * EE + e;
    float dtv = dt[o];
    float hv = h[o];
    float Bv = ssm[l * 160 + 128 + n];
    float Cv = ssm[l * 160 + 144 + n];
    float dA = __expf(dtv * A);
    s = s * dA + dtv * hv * Bv;
    float part = s * Cv;
    part += __shfl_xor(part, 1);
    part += __shfl_xor(part, 2);
    part += __shfl_xor(part, 4);
    part += __shfl_xor(part, 8);
    if (n == 0) {
      float gv = proj[(size_t)l * 2 * EE + EE + e];
      float yv = (part + hv * Dv) * (gv / (1.0f + __expf(-gv)));
      yb[o] = f2bf(yv);
    }
  }
}

// ---------------- fallback single-pass scan (small-ws safety) ----------------
__global__ __launch_bounds__(256) void scan_k(
    const float* __restrict__ dt, const float* __restrict__ h,
    const float* __restrict__ ssm, const float* __restrict__ A_log,
    const float* __restrict__ Dp, const float* __restrict__ proj,
    unsigned short* __restrict__ yb) {
  int tid = threadIdx.x;
  int n = tid & 15, el = tid >> 4;
  int e = blockIdx.x * 16 + el;
  float A = -__expf(A_log[e * NS + n]);
  float Dv = Dp[e];
  float s = 0.0f;
  float dtv = dt[e];
  float hv = h[e];
  float Bv = ssm[128 + n];
  float Cv = ssm[144 + n];
  float gv = proj[EE + e];
  for (int l = 0; l < LL; ++l) {
    float dt2 = 0.f, h2 = 0.f, B2 = 0.f, C2 = 0.f, g2 = 0.f;
    if (l + 1 < LL) {
      size_t o = (size_t)(l + 1) * EE + e;
      dt2 = dt[o];
      h2 = h[o];
      B2 = ssm[(l + 1) * 160 + 128 + n];
      C2 = ssm[(l + 1) * 160 + 144 + n];
      g2 = proj[(size_t)(l + 1) * 2 * EE + EE + e];
    }
    float dA = __expf(dtv * A);
    s = s * dA + dtv * hv * Bv;
    float part = s * Cv;
    part += __shfl_xor(part, 1);
    part += __shfl_xor(part, 2);
    part += __shfl_xor(part, 4);
    part += __shfl_xor(part, 8);
    if (n == 0) {
      float yv = (part + hv * Dv) * (gv / (1.0f + __expf(-gv)));
      yb[(size_t)l * EE + e] = f2bf(yv);
    }
    dtv = dt2; hv = h2; Bv = B2; Cv = C2; gv = g2;
  }
}

extern "C" void kernel_launch(void* const* d_in, const int* in_sizes, int n_in,
                              void* d_out, int out_size, void* d_ws, size_t ws_size,
                              hipStream_t stream) {
  const float* hs   = (const float*)d_in[0];
  const float* w1   = (const float*)d_in[1];
  const float* cw   = (const float*)d_in[2];
  const float* cb   = (const float*)d_in[3];
  const float* xw   = (const float*)d_in[4];
  const float* dtw  = (const float*)d_in[5];
  const float* dtb  = (const float*)d_in[6];
  const float* Alog = (const float*)d_in[7];
  const float* Dp   = (const float*)d_in[8];
  const float* ow   = (const float*)d_in[9];
  float* out = (float*)d_out;

  char* ws = (char*)d_ws;
  size_t off = 0;
  auto alloc = [&](size_t b) {
    char* p = ws + off;
    off += (b + 255) & ~(size_t)255;
    return p;
  };
  float* proj = (float*)alloc((size_t)LL * 2 * EE * 4);        // 67 MB
  float* hf   = (float*)alloc((size_t)LL * EE * 4);            // 33.5 MB
  unsigned short* hb = (unsigned short*)alloc((size_t)LL * EE * 2); // 16.8 MB
  float* dtf  = (float*)alloc((size_t)LL * EE * 4);            // 33.5 MB (aliased w/ w1b)
  unsigned short* w1b = (unsigned short*)dtf; // bf16 w1 (dead before dtf written)
  unsigned short* hsb = (unsigned short*)alloc((size_t)LL * HH * 2);   // 8.4 MB
  unsigned short* yb  = (unsigned short*)alloc((size_t)LL * EE * 2);   // 16.8 MB
  unsigned short* owb = (unsigned short*)alloc((size_t)HH * EE * 2);   // 16.8 MB
  unsigned short* xwb = (unsigned short*)alloc((size_t)160 * EE * 2);  // 1.3 MB
  float* ssm = (float*)alloc((size_t)LL * 160 * 4);                    // 1.3 MB
  unsigned short* dtin = (unsigned short*)alloc((size_t)LL * RR * 2);  // 0.5 MB
  unsigned short* dtwb = (unsigned short*)alloc((size_t)EE * RR * 2);  // 1.0 MB
  // chunked-scan state
  float* Pbuf = (float*)alloc((size_t)NC * EE * NS * 4);               // 16.8 MB
  float* Sbuf = (float*)alloc((size_t)NC * EE * NS * 4);               // 16.8 MB
  bool chunked = (off <= ws_size);

  auto cast = [&](const float* in, unsigned short* o, int nelem) {
    int n4 = nelem / 4;
    cast_bf16_k<<<(n4 + 255) / 256, 256, 0, stream>>>(in, o, n4);
  };
  cast(hs, hsb, LL * HH);
  cast(w1, w1b, 2 * EE * HH);
  cast(xw, xwb, 160 * EE);
  cast(dtw, dtwb, EE * RR);
  cast(ow, owb, HH * EE);

  auto gemm = [&](const unsigned short* A, const unsigned short* Bm, float* Cm,
                  int M, int N, int K) {
    int tilesN = (N + 127) / 128;
    int tilesM = M / 64;
    gemm_bt<<<tilesM * tilesN, 256, 0, stream>>>(A, Bm, Cm, M, N, K, tilesN);
  };

  // 1) proj = hs @ in_proj_w^T   [2048, 8192]
  gemm(hsb, w1b, proj, LL, 2 * EE, HH);
  // 2) causal depthwise conv + silu -> h (f32 + bf16)
  conv_silu_k<<<dim3(EE / 256, LL), 256, 0, stream>>>(proj, cw, cb, hf, hb);
  // 3) ssm = h @ x_proj_w^T   [2048, 160]
  gemm(hb, xwb, ssm, LL, 160, EE);
  // 4) dt input slice -> bf16
  dtcast_k<<<(LL * RR + 255) / 256, 256, 0, stream>>>(ssm, dtin, LL * RR);
  // 5) dt_raw = dtin @ dt_proj_w^T   [2048, 4096]
  gemm(dtin, dtwb, dtf, LL, EE, RR);
  // 6) dt = softplus(dt_raw + b)
  softplus_k<<<(LL * EE + 255) / 256, 256, 0, stream>>>(dtf, dtb, LL * EE);
  // 7) selective scan + gating -> y (bf16)
  if (chunked) {
    scan_partA<<<dim3(NC, EE / 16), 256, 0, stream>>>(dtf, hf, ssm, Alog, Pbuf, Sbuf);
    scan_chunkB<<<EE * NS / 256, 256, 0, stream>>>(Pbuf, Sbuf);
    scan_partC<<<dim3(NC, EE / 16), 256, 0, stream>>>(dtf, hf, ssm, Alog, Dp, proj,
                                                      Sbuf, yb);
  } else {
    scan_k<<<EE / 16, 256, 0, stream>>>(dtf, hf, ssm, Alog, Dp, proj, yb);
  }
  // 8) out = y @ out_proj_w^T   [2048, 2048]
  gemm(yb, owb, out, LL, HH, EE);
}

// Round 3
// 690.906 us; speedup vs baseline: 2.2641x; 1.5999x over previous
//
#include <hip/hip_runtime.h>

#define LL 2048
#define HH 2048
#define EE 4096
#define NS 16
#define RR 128
#define CT 32            // chunk timesteps
#define NC (LL / CT)     // 64 chunks
#define BM 128
#define BN 128
#define BK 64

typedef __bf16 bf16x8 __attribute__((ext_vector_type(8)));
typedef float f32x4 __attribute__((ext_vector_type(4)));

__device__ __forceinline__ unsigned short f2bf(float f) {
  union { float f; unsigned int u; } v; v.f = f;
  unsigned int r = v.u + 0x7fffu + ((v.u >> 16) & 1u);
  return (unsigned short)(r >> 16);
}

__device__ __forceinline__ void async_cp16(const unsigned short* g,
                                           unsigned short* l) {
  __builtin_amdgcn_global_load_lds(
      (const __attribute__((address_space(1))) unsigned int*)g,
      (__attribute__((address_space(3))) unsigned int*)l, 16, 0, 0);
}

// ---------------- fp32 -> bf16 cast (vectorized x4) ----------------
__global__ void cast_bf16_k(const float* __restrict__ in,
                            unsigned short* __restrict__ out, int n4) {
  int i = blockIdx.x * blockDim.x + threadIdx.x;
  if (i >= n4) return;
  float4 v = reinterpret_cast<const float4*>(in)[i];
  ushort4 o;
  o.x = f2bf(v.x); o.y = f2bf(v.y); o.z = f2bf(v.z); o.w = f2bf(v.w);
  reinterpret_cast<ushort4*>(out)[i] = o;
}

// ---------------- zero fill (float4) ----------------
__global__ void zero_k(float* __restrict__ p, int n4) {
  int i = blockIdx.x * blockDim.x + threadIdx.x;
  if (i >= n4) return;
  float4 z; z.x = z.y = z.z = z.w = 0.0f;
  reinterpret_cast<float4*>(p)[i] = z;
}

// ============ LDS-staged bf16 BT-GEMM: C[M,N] = A[M,K] * B[N,K]^T ============
// 256 thr = 4 waves (2x2), block tile 128x128, wave tile 64x64 (4x4 frags).
// BK=64; LDS 2x16KB, XOR-8 swizzle on 16B blocks: LDS[r][cb] = G[r][cb^(r&7)].
// Staged with global_load_lds width=16 (wave-uniform LDS base + lane*16).
// M, N multiples of 128; K multiple of 64. splitk>1 -> atomicAdd into C.
__global__ __launch_bounds__(256) void gemm_lds(
    const unsigned short* __restrict__ A,
    const unsigned short* __restrict__ B,
    float* __restrict__ C,
    int M, int N, int K, int tilesN, int splitk) {
  __shared__ __align__(16) unsigned short As[BM * BK];
  __shared__ __align__(16) unsigned short Bs[BN * BK];

  int bid = blockIdx.x;
  int groupSize = 8 * tilesN;
  int g = bid / groupSize, r = bid % groupSize;
  int tm = g * 8 + (r & 7);
  int tn = r >> 3;

  int Kslice = K / splitk;
  int k_begin = blockIdx.y * Kslice;
  int k_end = k_begin + Kslice;

  int tid = threadIdx.x;
  int lane = tid & 63;
  int wave = tid >> 6;
  int wm = wave & 1, wn = wave >> 1;
  int m16 = lane & 15, quad = lane >> 4;

  const unsigned short* Ab = A + (size_t)tm * BM * K;
  const unsigned short* Bb = B + (size_t)tn * BN * K;

  // staging geometry (per 16B block): blk = it*256 + tid, row = blk>>3,
  // lds col-block = blk&7, global col-block = (blk&7) ^ (row&7)
  int srow[4], sgcb[4];
#pragma unroll
  for (int it = 0; it < 4; ++it) {
    int blk = it * 256 + tid;
    srow[it] = blk >> 3;
    sgcb[it] = (blk & 7) ^ (srow[it] & 7);
  }
  int ldsbase = (tid & ~63) * 8;  // wave-uniform, in ushort units

  f32x4 acc[4][4];
#pragma unroll
  for (int i = 0; i < 4; ++i)
#pragma unroll
    for (int j = 0; j < 4; ++j)
#pragma unroll
      for (int t = 0; t < 4; ++t) acc[i][j][t] = 0.0f;

  for (int k0 = k_begin; k0 < k_end; k0 += BK) {
    __syncthreads();
#pragma unroll
    for (int it = 0; it < 4; ++it)
      async_cp16(Ab + (size_t)srow[it] * K + k0 + sgcb[it] * 8,
                 &As[it * 2048 + ldsbase]);
#pragma unroll
    for (int it = 0; it < 4; ++it)
      async_cp16(Bb + (size_t)srow[it] * K + k0 + sgcb[it] * 8,
                 &Bs[it * 2048 + ldsbase]);
    __syncthreads();
#pragma unroll
    for (int kk = 0; kk < 2; ++kk) {
      bf16x8 a[4], b[4];
#pragma unroll
      for (int i = 0; i < 4; ++i) {
        int rr = wm * 64 + i * 16 + m16;
        int cb = (kk << 2) + quad;
        a[i] = *reinterpret_cast<const bf16x8*>(
            &As[rr * BK + ((cb ^ (rr & 7)) << 3)]);
      }
#pragma unroll
      for (int j = 0; j < 4; ++j) {
        int rr = wn * 64 + j * 16 + m16;
        int cb = (kk << 2) + quad;
        b[j] = *reinterpret_cast<const bf16x8*>(
            &Bs[rr * BK + ((cb ^ (rr & 7)) << 3)]);
      }
#pragma unroll
      for (int i = 0; i < 4; ++i)
#pragma unroll
        for (int j = 0; j < 4; ++j)
          acc[i][j] =
              __builtin_amdgcn_mfma_f32_16x16x32_bf16(a[i], b[j], acc[i][j], 0, 0, 0);
    }
  }

  int rowB = tm * BM + wm * 64;
  int colB = tn * BN + wn * 64;
  if (splitk == 1) {
#pragma unroll
    for (int i = 0; i < 4; ++i)
#pragma unroll
      for (int j = 0; j < 4; ++j) {
        int col = colB + j * 16 + m16;
        int row0 = rowB + i * 16 + quad * 4;
#pragma unroll
        for (int t = 0; t < 4; ++t)
          C[(size_t)(row0 + t) * N + col] = acc[i][j][t];
      }
  } else {
#pragma unroll
    for (int i = 0; i < 4; ++i)
#pragma unroll
      for (int j = 0; j < 4; ++j) {
        int col = colB + j * 16 + m16;
        int row0 = rowB + i * 16 + quad * 4;
#pragma unroll
        for (int t = 0; t < 4; ++t)
          atomicAdd(&C[(size_t)(row0 + t) * N + col], acc[i][j][t]);
      }
  }
}

// ------------- direct (no-LDS) BT-GEMM for skinny N (x_proj) -------------
__global__ __launch_bounds__(256) void gemm_bt(
    const unsigned short* __restrict__ A,
    const unsigned short* __restrict__ B,
    float* __restrict__ C,
    int M, int N, int K, int tilesN, int splitk) {
  int bid = blockIdx.x;
  int groupSize = 8 * tilesN;
  int g = bid / groupSize, r = bid % groupSize;
  int tm = g * 8 + (r & 7);
  int tn = r >> 3;

  int Kslice = K / splitk;
  int k_begin = blockIdx.y * Kslice;
  int k_end = k_begin + Kslice;

  int tid = threadIdx.x;
  int wave = tid >> 6, lane = tid & 63;
  int wm = wave & 1, wn = wave >> 1;
  int m16 = lane & 15, quad = lane >> 4;
  int rowBase = tm * 64 + wm * 32;
  int colBase = tn * 128 + wn * 64;

  const unsigned short* a0p = A + (size_t)(rowBase + m16) * K + quad * 8;
  const unsigned short* a1p = A + (size_t)(rowBase + 16 + m16) * K + quad * 8;
  const unsigned short* bp[4];
  bool bok[4];
#pragma unroll
  for (int j = 0; j < 4; ++j) {
    int col = colBase + j * 16 + m16;
    bok[j] = (col < N);
    bp[j] = B + (size_t)(bok[j] ? col : 0) * K + quad * 8;
  }

  f32x4 acc[2][4];
#pragma unroll
  for (int i = 0; i < 2; ++i)
#pragma unroll
    for (int j = 0; j < 4; ++j)
#pragma unroll
      for (int t = 0; t < 4; ++t) acc[i][j][t] = 0.0f;

  bf16x8 zero8;
#pragma unroll
  for (int t = 0; t < 8; ++t) zero8[t] = (__bf16)0.0f;

  for (int k = k_begin; k < k_end; k += 32) {
    bf16x8 a0 = *reinterpret_cast<const bf16x8*>(a0p + k);
    bf16x8 a1 = *reinterpret_cast<const bf16x8*>(a1p + k);
    bf16x8 b[4];
#pragma unroll
    for (int j = 0; j < 4; ++j)
      b[j] = bok[j] ? *reinterpret_cast<const bf16x8*>(bp[j] + k) : zero8;
#pragma unroll
    for (int j = 0; j < 4; ++j) {
      acc[0][j] = __builtin_amdgcn_mfma_f32_16x16x32_bf16(a0, b[j], acc[0][j], 0, 0, 0);
      acc[1][j] = __builtin_amdgcn_mfma_f32_16x16x32_bf16(a1, b[j], acc[1][j], 0, 0, 0);
    }
  }

#pragma unroll
  for (int i = 0; i < 2; ++i)
#pragma unroll
    for (int j = 0; j < 4; ++j) {
      int col = colBase + j * 16 + m16;
      if (col >= N) continue;
      int row0 = rowBase + i * 16 + quad * 4;
      if (splitk == 1) {
#pragma unroll
        for (int t = 0; t < 4; ++t)
          C[(size_t)(row0 + t) * N + col] = acc[i][j][t];
      } else {
#pragma unroll
        for (int t = 0; t < 4; ++t)
          atomicAdd(&C[(size_t)(row0 + t) * N + col], acc[i][j][t]);
      }
    }
}

// ---------------- depthwise causal conv (K=4) + bias + silu ----------------
__global__ __launch_bounds__(256) void conv_silu_k(
    const float* __restrict__ proj, const float* __restrict__ cw,
    const float* __restrict__ cb, float* __restrict__ hf,
    unsigned short* __restrict__ hb) {
  int e = blockIdx.x * 256 + threadIdx.x;
  int l = blockIdx.y;
  float acc = cb[e];
#pragma unroll
  for (int k = 0; k < 4; ++k) {
    int lt = l - 3 + k;
    if (lt >= 0) acc += cw[e * 4 + k] * proj[(size_t)lt * (2 * EE) + e];
  }
  float s = acc / (1.0f + __expf(-acc));
  hf[(size_t)l * EE + e] = s;
  hb[(size_t)l * EE + e] = f2bf(s);
}

// ---------------- extract dt rows of ssm -> bf16 [L,128] ----------------
__global__ void dtcast_k(const float* __restrict__ ssm,
                         unsigned short* __restrict__ dtin, int n) {
  int i = blockIdx.x * blockDim.x + threadIdx.x;
  if (i >= n) return;
  int l = i >> 7, r = i & 127;
  dtin[i] = f2bf(ssm[l * 160 + r]);
}

// ---------------- bias + softplus, in place on dt_raw [L,E] ----------------
__global__ void softplus_k(float* __restrict__ dt, const float* __restrict__ db,
                           int n) {
  int i = blockIdx.x * blockDim.x + threadIdx.x;
  if (i >= n) return;
  float x = dt[i] + db[i & (EE - 1)];
  dt[i] = (x > 20.0f) ? x : log1pf(__expf(x));
}

// ================= chunked selective scan =================
__global__ __launch_bounds__(256) void scan_partA(
    const float* __restrict__ dt, const float* __restrict__ h,
    const float* __restrict__ ssm, const float* __restrict__ A_log,
    float* __restrict__ P, float* __restrict__ S) {
  int tid = threadIdx.x;
  int n = tid & 15, el = tid >> 4;
  int c = blockIdx.x, eg = blockIdx.y;
  int e = eg * 16 + el;
  float A = -__expf(A_log[e * NS + n]);
  float s = 0.0f, p = 1.0f;
  int l0 = c * CT;
#pragma unroll 4
  for (int t = 0; t < CT; ++t) {
    int l = l0 + t;
    size_t o = (size_t)l * EE + e;
    float dtv = dt[o];
    float hv = h[o];
    float Bv = ssm[l * 160 + 128 + n];
    float dA = __expf(dtv * A);
    s = s * dA + dtv * hv * Bv;
    p *= dA;
  }
  size_t idx = ((size_t)c * EE + e) * NS + n;
  P[idx] = p;
  S[idx] = s;
}

__global__ __launch_bounds__(256) void scan_chunkB(
    const float* __restrict__ P, float* __restrict__ S) {
  int gidx = blockIdx.x * 256 + threadIdx.x;
  float s = 0.0f;
  float pv = P[gidx], sv = S[gidx];
  for (int c = 0; c < NC; ++c) {
    float pn = 0.0f, sn = 0.0f;
    if (c + 1 < NC) {
      size_t i2 = (size_t)(c + 1) * (EE * NS) + gidx;
      pn = P[i2];
      sn = S[i2];
    }
    float s_next = s * pv + sv;
    S[(size_t)c * (EE * NS) + gidx] = s;
    s = s_next;
    pv = pn; sv = sn;
  }
}

__global__ __launch_bounds__(256) void scan_partC(
    const float* __restrict__ dt, const float* __restrict__ h,
    const float* __restrict__ ssm, const float* __restrict__ A_log,
    const float* __restrict__ Dp, const float* __restrict__ proj,
    const float* __restrict__ Sinit, unsigned short* __restrict__ yb) {
  int tid = threadIdx.x;
  int n = tid & 15, el = tid >> 4;
  int c = blockIdx.x, eg = blockIdx.y;
  int e = eg * 16 + el;
  float A = -__expf(A_log[e * NS + n]);
  float Dv = Dp[e];
  float s = Sinit[((size_t)c * EE + e) * NS + n];
  int l0 = c * CT;
#pragma unroll 2
  for (int t = 0; t < CT; ++t) {
    int l = l0 + t;
    size_t o = (size_t)l * EE + e;
    float dtv = dt[o];
    float hv = h[o];
    float Bv = ssm[l * 160 + 128 + n];
    float Cv = ssm[l * 160 + 144 + n];
    float dA = __expf(dtv * A);
    s = s * dA + dtv * hv * Bv;
    float part = s * Cv;
    part += __shfl_xor(part, 1);
    part += __shfl_xor(part, 2);
    part += __shfl_xor(part, 4);
    part += __shfl_xor(part, 8);
    if (n == 0) {
      float gv = proj[(size_t)l * 2 * EE + EE + e];
      float yv = (part + hv * Dv) * (gv / (1.0f + __expf(-gv)));
      yb[o] = f2bf(yv);
    }
  }
}

extern "C" void kernel_launch(void* const* d_in, const int* in_sizes, int n_in,
                              void* d_out, int out_size, void* d_ws, size_t ws_size,
                              hipStream_t stream) {
  const float* hs   = (const float*)d_in[0];
  const float* w1   = (const float*)d_in[1];
  const float* cw   = (const float*)d_in[2];
  const float* cb   = (const float*)d_in[3];
  const float* xw   = (const float*)d_in[4];
  const float* dtw  = (const float*)d_in[5];
  const float* dtb  = (const float*)d_in[6];
  const float* Alog = (const float*)d_in[7];
  const float* Dp   = (const float*)d_in[8];
  const float* ow   = (const float*)d_in[9];
  float* out = (float*)d_out;

  char* ws = (char*)d_ws;
  size_t off = 0;
  auto alloc = [&](size_t b) {
    char* p = ws + off;
    off += (b + 255) & ~(size_t)255;
    return p;
  };
  float* proj = (float*)alloc((size_t)LL * 2 * EE * 4);
  float* hf   = (float*)alloc((size_t)LL * EE * 4);
  unsigned short* hb = (unsigned short*)alloc((size_t)LL * EE * 2);
  float* dtf  = (float*)alloc((size_t)LL * EE * 4);
  unsigned short* w1b = (unsigned short*)dtf;  // aliased: dead before dtf written
  unsigned short* hsb = (unsigned short*)alloc((size_t)LL * HH * 2);
  unsigned short* yb  = (unsigned short*)alloc((size_t)LL * EE * 2);
  unsigned short* owb = (unsigned short*)alloc((size_t)HH * EE * 2);
  unsigned short* xwb = (unsigned short*)alloc((size_t)160 * EE * 2);
  float* ssm = (float*)alloc((size_t)LL * 160 * 4);
  unsigned short* dtin = (unsigned short*)alloc((size_t)LL * RR * 2);
  unsigned short* dtwb = (unsigned short*)alloc((size_t)EE * RR * 2);
  float* Pbuf = (float*)alloc((size_t)NC * EE * NS * 4);
  float* Sbuf = (float*)alloc((size_t)NC * EE * NS * 4);

  auto cast = [&](const float* in, unsigned short* o, int nelem) {
    int n4 = nelem / 4;
    cast_bf16_k<<<(n4 + 255) / 256, 256, 0, stream>>>(in, o, n4);
  };
  cast(hs, hsb, LL * HH);
  cast(w1, w1b, 2 * EE * HH);
  cast(xw, xwb, 160 * EE);
  cast(dtw, dtwb, EE * RR);
  cast(ow, owb, HH * EE);
  // zero accumulation targets for split-K atomics
  zero_k<<<(LL * 160 / 4 + 255) / 256, 256, 0, stream>>>(ssm, LL * 160 / 4);
  zero_k<<<(LL * HH / 4 + 255) / 256, 256, 0, stream>>>(out, LL * HH / 4);

  auto gemmL = [&](const unsigned short* A, const unsigned short* Bm, float* Cm,
                   int M, int N, int K, int splitk) {
    int tilesN = N / BN, tilesM = M / BM;
    gemm_lds<<<dim3(tilesM * tilesN, splitk), 256, 0, stream>>>(
        A, Bm, Cm, M, N, K, tilesN, splitk);
  };

  // 1) proj = hs @ in_proj_w^T   [2048, 8192] k=2048
  gemmL(hsb, w1b, proj, LL, 2 * EE, HH, 1);
  // 2) causal depthwise conv + silu -> h
  conv_silu_k<<<dim3(EE / 256, LL), 256, 0, stream>>>(proj, cw, cb, hf, hb);
  // 3) ssm = h @ x_proj_w^T   [2048, 160] k=4096, split-K=8 (skinny N)
  {
    int tilesN = (160 + 127) / 128, tilesM = LL / 64;
    gemm_bt<<<dim3(tilesM * tilesN, 8), 256, 0, stream>>>(
        hb, xwb, ssm, LL, 160, EE, tilesN, 8);
  }
  // 4) dt input slice -> bf16
  dtcast_k<<<(LL * RR + 255) / 256, 256, 0, stream>>>(ssm, dtin, LL * RR);
  // 5) dt_raw = dtin @ dt_proj_w^T   [2048, 4096] k=128
  gemmL(dtin, dtwb, dtf, LL, EE, RR, 1);
  // 6) dt = softplus(dt_raw + b)
  softplus_k<<<(LL * EE + 255) / 256, 256, 0, stream>>>(dtf, dtb, LL * EE);
  // 7) chunked selective scan + gating -> y (bf16)
  scan_partA<<<dim3(NC, EE / 16), 256, 0, stream>>>(dtf, hf, ssm, Alog, Pbuf, Sbuf);
  scan_chunkB<<<EE * NS / 256, 256, 0, stream>>>(Pbuf, Sbuf);
  scan_partC<<<dim3(NC, EE / 16), 256, 0, stream>>>(dtf, hf, ssm, Alog, Dp, proj,
                                                    Sbuf, yb);
  // 8) out = y @ out_proj_w^T   [2048, 2048] k=4096, split-K=2 for occupancy
  gemmL(yb, owb, out, LL, HH, EE, 2);
}

// Round 4
// 512.687 us; speedup vs baseline: 3.0512x; 1.3476x over previous
//
#include <hip/hip_runtime.h>

#define LL 2048
#define HH 2048
#define EE 4096
#define NS 16
#define RR 128
#define CT 32            // chunk timesteps
#define NC (LL / CT)     // 64 chunks
#define BM 128
#define BN 128
#define BK 64

typedef __bf16 bf16x8 __attribute__((ext_vector_type(8)));
typedef float f32x4 __attribute__((ext_vector_type(4)));

__device__ __forceinline__ unsigned short f2bf(float f) {
  union { float f; unsigned int u; } v; v.f = f;
  unsigned int r = v.u + 0x7fffu + ((v.u >> 16) & 1u);
  return (unsigned short)(r >> 16);
}

__device__ __forceinline__ void async_cp16(const unsigned short* g,
                                           unsigned short* l) {
  __builtin_amdgcn_global_load_lds(
      (const __attribute__((address_space(1))) unsigned int*)g,
      (__attribute__((address_space(3))) unsigned int*)l, 16, 0, 0);
}

// ---------------- fp32 -> bf16 cast (vectorized x4) ----------------
__global__ void cast_bf16_k(const float* __restrict__ in,
                            unsigned short* __restrict__ out, int n4) {
  int i = blockIdx.x * blockDim.x + threadIdx.x;
  if (i >= n4) return;
  float4 v = reinterpret_cast<const float4*>(in)[i];
  ushort4 o;
  o.x = f2bf(v.x); o.y = f2bf(v.y); o.z = f2bf(v.z); o.w = f2bf(v.w);
  reinterpret_cast<ushort4*>(out)[i] = o;
}

// ---------------- zero fill (float4) ----------------
__global__ void zero_k(float* __restrict__ p, int n4) {
  int i = blockIdx.x * blockDim.x + threadIdx.x;
  if (i >= n4) return;
  float4 z; z.x = z.y = z.z = z.w = 0.0f;
  reinterpret_cast<float4*>(p)[i] = z;
}

// ============ LDS-staged bf16 BT-GEMM: C[M,N] = A[M,K] * B[N,K]^T ============
__global__ __launch_bounds__(256) void gemm_lds(
    const unsigned short* __restrict__ A,
    const unsigned short* __restrict__ B,
    float* __restrict__ C,
    int M, int N, int K, int tilesN, int splitk) {
  __shared__ __align__(16) unsigned short As[BM * BK];
  __shared__ __align__(16) unsigned short Bs[BN * BK];

  int bid = blockIdx.x;
  int groupSize = 8 * tilesN;
  int g = bid / groupSize, r = bid % groupSize;
  int tm = g * 8 + (r & 7);
  int tn = r >> 3;

  int Kslice = K / splitk;
  int k_begin = blockIdx.y * Kslice;
  int k_end = k_begin + Kslice;

  int tid = threadIdx.x;
  int lane = tid & 63;
  int wave = tid >> 6;
  int wm = wave & 1, wn = wave >> 1;
  int m16 = lane & 15, quad = lane >> 4;

  const unsigned short* Ab = A + (size_t)tm * BM * K;
  const unsigned short* Bb = B + (size_t)tn * BN * K;

  int srow[4], sgcb[4];
#pragma unroll
  for (int it = 0; it < 4; ++it) {
    int blk = it * 256 + tid;
    srow[it] = blk >> 3;
    sgcb[it] = (blk & 7) ^ (srow[it] & 7);
  }
  int ldsbase = (tid & ~63) * 8;  // wave-uniform, in ushort units

  f32x4 acc[4][4];
#pragma unroll
  for (int i = 0; i < 4; ++i)
#pragma unroll
    for (int j = 0; j < 4; ++j)
#pragma unroll
      for (int t = 0; t < 4; ++t) acc[i][j][t] = 0.0f;

  for (int k0 = k_begin; k0 < k_end; k0 += BK) {
    __syncthreads();
#pragma unroll
    for (int it = 0; it < 4; ++it)
      async_cp16(Ab + (size_t)srow[it] * K + k0 + sgcb[it] * 8,
                 &As[it * 2048 + ldsbase]);
#pragma unroll
    for (int it = 0; it < 4; ++it)
      async_cp16(Bb + (size_t)srow[it] * K + k0 + sgcb[it] * 8,
                 &Bs[it * 2048 + ldsbase]);
    __syncthreads();
#pragma unroll
    for (int kk = 0; kk < 2; ++kk) {
      bf16x8 a[4], b[4];
#pragma unroll
      for (int i = 0; i < 4; ++i) {
        int rr = wm * 64 + i * 16 + m16;
        int cb = (kk << 2) + quad;
        a[i] = *reinterpret_cast<const bf16x8*>(
            &As[rr * BK + ((cb ^ (rr & 7)) << 3)]);
      }
#pragma unroll
      for (int j = 0; j < 4; ++j) {
        int rr = wn * 64 + j * 16 + m16;
        int cb = (kk << 2) + quad;
        b[j] = *reinterpret_cast<const bf16x8*>(
            &Bs[rr * BK + ((cb ^ (rr & 7)) << 3)]);
      }
#pragma unroll
      for (int i = 0; i < 4; ++i)
#pragma unroll
        for (int j = 0; j < 4; ++j)
          acc[i][j] =
              __builtin_amdgcn_mfma_f32_16x16x32_bf16(a[i], b[j], acc[i][j], 0, 0, 0);
    }
  }

  int rowB = tm * BM + wm * 64;
  int colB = tn * BN + wn * 64;
  if (splitk == 1) {
#pragma unroll
    for (int i = 0; i < 4; ++i)
#pragma unroll
      for (int j = 0; j < 4; ++j) {
        int col = colB + j * 16 + m16;
        int row0 = rowB + i * 16 + quad * 4;
#pragma unroll
        for (int t = 0; t < 4; ++t)
          C[(size_t)(row0 + t) * N + col] = acc[i][j][t];
      }
  } else {
#pragma unroll
    for (int i = 0; i < 4; ++i)
#pragma unroll
      for (int j = 0; j < 4; ++j) {
        int col = colB + j * 16 + m16;
        int row0 = rowB + i * 16 + quad * 4;
#pragma unroll
        for (int t = 0; t < 4; ++t)
          atomicAdd(&C[(size_t)(row0 + t) * N + col], acc[i][j][t]);
      }
  }
}

// ------------- direct (no-LDS) BT-GEMM for skinny N (x_proj) -------------
__global__ __launch_bounds__(256) void gemm_bt(
    const unsigned short* __restrict__ A,
    const unsigned short* __restrict__ B,
    float* __restrict__ C,
    int M, int N, int K, int tilesN, int splitk) {
  int bid = blockIdx.x;
  int groupSize = 8 * tilesN;
  int g = bid / groupSize, r = bid % groupSize;
  int tm = g * 8 + (r & 7);
  int tn = r >> 3;

  int Kslice = K / splitk;
  int k_begin = blockIdx.y * Kslice;
  int k_end = k_begin + Kslice;

  int tid = threadIdx.x;
  int wave = tid >> 6, lane = tid & 63;
  int wm = wave & 1, wn = wave >> 1;
  int m16 = lane & 15, quad = lane >> 4;
  int rowBase = tm * 64 + wm * 32;
  int colBase = tn * 128 + wn * 64;

  const unsigned short* a0p = A + (size_t)(rowBase + m16) * K + quad * 8;
  const unsigned short* a1p = A + (size_t)(rowBase + 16 + m16) * K + quad * 8;
  const unsigned short* bp[4];
  bool bok[4];
#pragma unroll
  for (int j = 0; j < 4; ++j) {
    int col = colBase + j * 16 + m16;
    bok[j] = (col < N);
    bp[j] = B + (size_t)(bok[j] ? col : 0) * K + quad * 8;
  }

  f32x4 acc[2][4];
#pragma unroll
  for (int i = 0; i < 2; ++i)
#pragma unroll
    for (int j = 0; j < 4; ++j)
#pragma unroll
      for (int t = 0; t < 4; ++t) acc[i][j][t] = 0.0f;

  bf16x8 zero8;
#pragma unroll
  for (int t = 0; t < 8; ++t) zero8[t] = (__bf16)0.0f;

  for (int k = k_begin; k < k_end; k += 32) {
    bf16x8 a0 = *reinterpret_cast<const bf16x8*>(a0p + k);
    bf16x8 a1 = *reinterpret_cast<const bf16x8*>(a1p + k);
    bf16x8 b[4];
#pragma unroll
    for (int j = 0; j < 4; ++j)
      b[j] = bok[j] ? *reinterpret_cast<const bf16x8*>(bp[j] + k) : zero8;
#pragma unroll
    for (int j = 0; j < 4; ++j) {
      acc[0][j] = __builtin_amdgcn_mfma_f32_16x16x32_bf16(a0, b[j], acc[0][j], 0, 0, 0);
      acc[1][j] = __builtin_amdgcn_mfma_f32_16x16x32_bf16(a1, b[j], acc[1][j], 0, 0, 0);
    }
  }

#pragma unroll
  for (int i = 0; i < 2; ++i)
#pragma unroll
    for (int j = 0; j < 4; ++j) {
      int col = colBase + j * 16 + m16;
      if (col >= N) continue;
      int row0 = rowBase + i * 16 + quad * 4;
      if (splitk == 1) {
#pragma unroll
        for (int t = 0; t < 4; ++t)
          C[(size_t)(row0 + t) * N + col] = acc[i][j][t];
      } else {
#pragma unroll
        for (int t = 0; t < 4; ++t)
          atomicAdd(&C[(size_t)(row0 + t) * N + col], acc[i][j][t]);
      }
    }
}

// ---------------- depthwise causal conv (K=4) + bias + silu ----------------
__global__ __launch_bounds__(256) void conv_silu_k(
    const float* __restrict__ proj, const float* __restrict__ cw,
    const float* __restrict__ cb, float* __restrict__ hf,
    unsigned short* __restrict__ hb) {
  int e = blockIdx.x * 256 + threadIdx.x;
  int l = blockIdx.y;
  float acc = cb[e];
#pragma unroll
  for (int k = 0; k < 4; ++k) {
    int lt = l - 3 + k;
    if (lt >= 0) acc += cw[e * 4 + k] * proj[(size_t)lt * (2 * EE) + e];
  }
  float s = acc / (1.0f + __expf(-acc));
  hf[(size_t)l * EE + e] = s;
  hb[(size_t)l * EE + e] = f2bf(s);
}

// ---------------- extract dt rows of ssm -> bf16 [L,128] ----------------
__global__ void dtcast_k(const float* __restrict__ ssm,
                         unsigned short* __restrict__ dtin, int n) {
  int i = blockIdx.x * blockDim.x + threadIdx.x;
  if (i >= n) return;
  int l = i >> 7, r = i & 127;
  dtin[i] = f2bf(ssm[l * 160 + r]);
}

// ---------------- bias + softplus, in place on dt_raw [L,E] ----------------
__global__ void softplus_k(float* __restrict__ dt, const float* __restrict__ db,
                           int n) {
  int i = blockIdx.x * blockDim.x + threadIdx.x;
  if (i >= n) return;
  float x = dt[i] + db[i & (EE - 1)];
  dt[i] = (x > 20.0f) ? x : log1pf(__expf(x));
}

// ================= chunked selective scan (16 states per thread) ===========
// thread = (chunk c, channel e); all NS=16 states live in registers.
// B/C rows of ssm are block-uniform -> float4 broadcast loads.

// Pass A: local scan from s=0 over CT steps; emit P = prod(dA), S = final.
__global__ __launch_bounds__(256) void scan_partA(
    const float* __restrict__ dt, const float* __restrict__ h,
    const float* __restrict__ ssm, const float* __restrict__ A_log,
    float* __restrict__ P, float* __restrict__ S) {
  int e = blockIdx.y * 256 + threadIdx.x;
  int c = blockIdx.x;
  float Aa[16];
#pragma unroll
  for (int q = 0; q < 4; ++q) {
    float4 a = reinterpret_cast<const float4*>(&A_log[(size_t)e * NS])[q];
    Aa[q * 4 + 0] = -__expf(a.x);
    Aa[q * 4 + 1] = -__expf(a.y);
    Aa[q * 4 + 2] = -__expf(a.z);
    Aa[q * 4 + 3] = -__expf(a.w);
  }
  float s[16], p[16];
#pragma unroll
  for (int n = 0; n < 16; ++n) { s[n] = 0.0f; p[n] = 1.0f; }
  int l0 = c * CT;
#pragma unroll 2
  for (int t = 0; t < CT; ++t) {
    int l = l0 + t;
    size_t o = (size_t)l * EE + e;
    float dtv = dt[o];
    float hv = h[o];
    float Bv[16];
#pragma unroll
    for (int q = 0; q < 4; ++q)
      *reinterpret_cast<float4*>(&Bv[q * 4]) =
          reinterpret_cast<const float4*>(&ssm[(size_t)l * 160 + 128])[q];
    float z = dtv * hv;
#pragma unroll
    for (int n = 0; n < 16; ++n) {
      float dA = __expf(dtv * Aa[n]);
      s[n] = s[n] * dA + z * Bv[n];
      p[n] *= dA;
    }
  }
  size_t base = ((size_t)c * EE + e) * NS;
#pragma unroll
  for (int q = 0; q < 4; ++q) {
    reinterpret_cast<float4*>(&P[base])[q] = *reinterpret_cast<float4*>(&p[q * 4]);
    reinterpret_cast<float4*>(&S[base])[q] = *reinterpret_cast<float4*>(&s[q * 4]);
  }
}

// Pass B: inter-chunk prefix scan over NC chunks, in place: S[c] <- s_init[c].
__global__ __launch_bounds__(256) void scan_chunkB(
    const float* __restrict__ P, float* __restrict__ S) {
  int gidx = blockIdx.x * 256 + threadIdx.x;
  float s = 0.0f;
  float pv = P[gidx], sv = S[gidx];
  for (int c = 0; c < NC; ++c) {
    float pn = 0.0f, sn = 0.0f;
    if (c + 1 < NC) {
      size_t i2 = (size_t)(c + 1) * (EE * NS) + gidx;
      pn = P[i2];
      sn = S[i2];
    }
    float s_next = s * pv + sv;
    S[(size_t)c * (EE * NS) + gidx] = s;
    s = s_next;
    pv = pn; sv = sn;
  }
}

// Pass C: rescan seeded with s_init; y = sum_n(s*C) + h*D, gated silu, bf16.
__global__ __launch_bounds__(256) void scan_partC(
    const float* __restrict__ dt, const float* __restrict__ h,
    const float* __restrict__ ssm, const float* __restrict__ A_log,
    const float* __restrict__ Dp, const float* __restrict__ proj,
    const float* __restrict__ Sinit, unsigned short* __restrict__ yb) {
  int e = blockIdx.y * 256 + threadIdx.x;
  int c = blockIdx.x;
  float Aa[16];
#pragma unroll
  for (int q = 0; q < 4; ++q) {
    float4 a = reinterpret_cast<const float4*>(&A_log[(size_t)e * NS])[q];
    Aa[q * 4 + 0] = -__expf(a.x);
    Aa[q * 4 + 1] = -__expf(a.y);
    Aa[q * 4 + 2] = -__expf(a.z);
    Aa[q * 4 + 3] = -__expf(a.w);
  }
  float Dv = Dp[e];
  float s[16];
  size_t base = ((size_t)c * EE + e) * NS;
#pragma unroll
  for (int q = 0; q < 4; ++q)
    *reinterpret_cast<float4*>(&s[q * 4]) =
        reinterpret_cast<const float4*>(&Sinit[base])[q];
  int l0 = c * CT;
#pragma unroll 2
  for (int t = 0; t < CT; ++t) {
    int l = l0 + t;
    size_t o = (size_t)l * EE + e;
    float dtv = dt[o];
    float hv = h[o];
    float Bv[16], Cv[16];
#pragma unroll
    for (int q = 0; q < 4; ++q) {
      *reinterpret_cast<float4*>(&Bv[q * 4]) =
          reinterpret_cast<const float4*>(&ssm[(size_t)l * 160 + 128])[q];
      *reinterpret_cast<float4*>(&Cv[q * 4]) =
          reinterpret_cast<const float4*>(&ssm[(size_t)l * 160 + 144])[q];
    }
    float z = dtv * hv;
    float y = 0.0f;
#pragma unroll
    for (int n = 0; n < 16; ++n) {
      float dA = __expf(dtv * Aa[n]);
      s[n] = s[n] * dA + z * Bv[n];
      y += s[n] * Cv[n];
    }
    float gv = proj[(size_t)l * 2 * EE + EE + e];
    float yv = (y + hv * Dv) * (gv / (1.0f + __expf(-gv)));
    yb[o] = f2bf(yv);
  }
}

extern "C" void kernel_launch(void* const* d_in, const int* in_sizes, int n_in,
                              void* d_out, int out_size, void* d_ws, size_t ws_size,
                              hipStream_t stream) {
  const float* hs   = (const float*)d_in[0];
  const float* w1   = (const float*)d_in[1];
  const float* cw   = (const float*)d_in[2];
  const float* cb   = (const float*)d_in[3];
  const float* xw   = (const float*)d_in[4];
  const float* dtw  = (const float*)d_in[5];
  const float* dtb  = (const float*)d_in[6];
  const float* Alog = (const float*)d_in[7];
  const float* Dp   = (const float*)d_in[8];
  const float* ow   = (const float*)d_in[9];
  float* out = (float*)d_out;

  char* ws = (char*)d_ws;
  size_t off = 0;
  auto alloc = [&](size_t b) {
    char* p = ws + off;
    off += (b + 255) & ~(size_t)255;
    return p;
  };
  float* proj = (float*)alloc((size_t)LL * 2 * EE * 4);
  float* hf   = (float*)alloc((size_t)LL * EE * 4);
  unsigned short* hb = (unsigned short*)alloc((size_t)LL * EE * 2);
  float* dtf  = (float*)alloc((size_t)LL * EE * 4);
  unsigned short* w1b = (unsigned short*)dtf;  // aliased: dead before dtf written
  unsigned short* hsb = (unsigned short*)alloc((size_t)LL * HH * 2);
  unsigned short* yb  = (unsigned short*)alloc((size_t)LL * EE * 2);
  unsigned short* owb = (unsigned short*)alloc((size_t)HH * EE * 2);
  unsigned short* xwb = (unsigned short*)alloc((size_t)160 * EE * 2);
  float* ssm = (float*)alloc((size_t)LL * 160 * 4);
  unsigned short* dtin = (unsigned short*)alloc((size_t)LL * RR * 2);
  unsigned short* dtwb = (unsigned short*)alloc((size_t)EE * RR * 2);
  float* Pbuf = (float*)alloc((size_t)NC * EE * NS * 4);
  float* Sbuf = (float*)alloc((size_t)NC * EE * NS * 4);

  auto cast = [&](const float* in, unsigned short* o, int nelem) {
    int n4 = nelem / 4;
    cast_bf16_k<<<(n4 + 255) / 256, 256, 0, stream>>>(in, o, n4);
  };
  cast(hs, hsb, LL * HH);
  cast(w1, w1b, 2 * EE * HH);
  cast(xw, xwb, 160 * EE);
  cast(dtw, dtwb, EE * RR);
  cast(ow, owb, HH * EE);
  // zero accumulation targets for split-K atomics
  zero_k<<<(LL * 160 / 4 + 255) / 256, 256, 0, stream>>>(ssm, LL * 160 / 4);
  zero_k<<<(LL * HH / 4 + 255) / 256, 256, 0, stream>>>(out, LL * HH / 4);

  auto gemmL = [&](const unsigned short* A, const unsigned short* Bm, float* Cm,
                   int M, int N, int K, int splitk) {
    int tilesN = N / BN, tilesM = M / BM;
    gemm_lds<<<dim3(tilesM * tilesN, splitk), 256, 0, stream>>>(
        A, Bm, Cm, M, N, K, tilesN, splitk);
  };

  // 1) proj = hs @ in_proj_w^T   [2048, 8192] k=2048
  gemmL(hsb, w1b, proj, LL, 2 * EE, HH, 1);
  // 2) causal depthwise conv + silu -> h
  conv_silu_k<<<dim3(EE / 256, LL), 256, 0, stream>>>(proj, cw, cb, hf, hb);
  // 3) ssm = h @ x_proj_w^T   [2048, 160] k=4096, split-K=8 (skinny N)
  {
    int tilesN = (160 + 127) / 128, tilesM = LL / 64;
    gemm_bt<<<dim3(tilesM * tilesN, 8), 256, 0, stream>>>(
        hb, xwb, ssm, LL, 160, EE, tilesN, 8);
  }
  // 4) dt input slice -> bf16
  dtcast_k<<<(LL * RR + 255) / 256, 256, 0, stream>>>(ssm, dtin, LL * RR);
  // 5) dt_raw = dtin @ dt_proj_w^T   [2048, 4096] k=128
  gemmL(dtin, dtwb, dtf, LL, EE, RR, 1);
  // 6) dt = softplus(dt_raw + b)
  softplus_k<<<(LL * EE + 255) / 256, 256, 0, stream>>>(dtf, dtb, LL * EE);
  // 7) chunked selective scan + gating -> y (bf16)
  scan_partA<<<dim3(NC, EE / 256), 256, 0, stream>>>(dtf, hf, ssm, Alog, Pbuf, Sbuf);
  scan_chunkB<<<EE * NS / 256, 256, 0, stream>>>(Pbuf, Sbuf);
  scan_partC<<<dim3(NC, EE / 256), 256, 0, stream>>>(dtf, hf, ssm, Alog, Dp, proj,
                                                     Sbuf, yb);
  // 8) out = y @ out_proj_w^T   [2048, 2048] k=4096, split-K=2 for occupancy
  gemmL(yb, owb, out, LL, HH, EE, 2);
}

// Round 5
// 473.097 us; speedup vs baseline: 3.3065x; 1.0837x over previous
//
#include <hip/hip_runtime.h>

#define LL 2048
#define HH 2048
#define EE 4096
#define NS 16
#define RR 128
#define CT 32            // chunk timesteps
#define NC (LL / CT)     // 64 chunks
#define BM 128
#define BN 128
#define BK 64

typedef __bf16 bf16x8 __attribute__((ext_vector_type(8)));
typedef float f32x4 __attribute__((ext_vector_type(4)));

__device__ __forceinline__ unsigned short f2bf(float f) {
  union { float f; unsigned int u; } v; v.f = f;
  unsigned int r = v.u + 0x7fffu + ((v.u >> 16) & 1u);
  return (unsigned short)(r >> 16);
}

__device__ __forceinline__ float bf2f(unsigned short u) {
  union { unsigned int i; float f; } v;
  v.i = ((unsigned int)u) << 16;
  return v.f;
}

__device__ __forceinline__ void async_cp16(const unsigned short* g,
                                           unsigned short* l) {
  __builtin_amdgcn_global_load_lds(
      (const __attribute__((address_space(1))) unsigned int*)g,
      (__attribute__((address_space(3))) unsigned int*)l, 16, 0, 0);
}

// ---------------- fp32 -> bf16 cast (vectorized x4) ----------------
__global__ void cast_bf16_k(const float* __restrict__ in,
                            unsigned short* __restrict__ out, int n4) {
  int i = blockIdx.x * blockDim.x + threadIdx.x;
  if (i >= n4) return;
  float4 v = reinterpret_cast<const float4*>(in)[i];
  ushort4 o;
  o.x = f2bf(v.x); o.y = f2bf(v.y); o.z = f2bf(v.z); o.w = f2bf(v.w);
  reinterpret_cast<ushort4*>(out)[i] = o;
}

// ---------------- zero fill (float4) ----------------
__global__ void zero_k(float* __restrict__ p, int n4) {
  int i = blockIdx.x * blockDim.x + threadIdx.x;
  if (i >= n4) return;
  float4 z; z.x = z.y = z.z = z.w = 0.0f;
  reinterpret_cast<float4*>(p)[i] = z;
}

// ============ LDS-staged bf16 BT-GEMM: C[M,N] = A[M,K] * B[N,K]^T ============
// XCD swizzle: tnInner = bid&7 so (with round-robin bid->XCD) each XCD keeps
// ONE B-tile L2-resident while tm sweeps fastest; A panel streams.
// Requires tilesN % 8 == 0.
__global__ __launch_bounds__(256) void gemm_lds(
    const unsigned short* __restrict__ A,
    const unsigned short* __restrict__ B,
    float* __restrict__ C,
    int M, int N, int K, int tilesM, int splitk) {
  __shared__ __align__(16) unsigned short As[BM * BK];
  __shared__ __align__(16) unsigned short Bs[BN * BK];

  int bid = blockIdx.x;
  int tnInner = bid & 7;
  int rest = bid >> 3;
  int tm = rest % tilesM;
  int tnOuter = rest / tilesM;
  int tn = tnOuter * 8 + tnInner;

  int Kslice = K / splitk;
  int k_begin = blockIdx.y * Kslice;
  int k_end = k_begin + Kslice;

  int tid = threadIdx.x;
  int lane = tid & 63;
  int wave = tid >> 6;
  int wm = wave & 1, wn = wave >> 1;
  int m16 = lane & 15, quad = lane >> 4;

  const unsigned short* Ab = A + (size_t)tm * BM * K;
  const unsigned short* Bb = B + (size_t)tn * BN * K;

  int srow[4], sgcb[4];
#pragma unroll
  for (int it = 0; it < 4; ++it) {
    int blk = it * 256 + tid;
    srow[it] = blk >> 3;
    sgcb[it] = (blk & 7) ^ (srow[it] & 7);
  }
  int ldsbase = (tid & ~63) * 8;  // wave-uniform, in ushort units

  f32x4 acc[4][4];
#pragma unroll
  for (int i = 0; i < 4; ++i)
#pragma unroll
    for (int j = 0; j < 4; ++j)
#pragma unroll
      for (int t = 0; t < 4; ++t) acc[i][j][t] = 0.0f;

  for (int k0 = k_begin; k0 < k_end; k0 += BK) {
    __syncthreads();
#pragma unroll
    for (int it = 0; it < 4; ++it)
      async_cp16(Ab + (size_t)srow[it] * K + k0 + sgcb[it] * 8,
                 &As[it * 2048 + ldsbase]);
#pragma unroll
    for (int it = 0; it < 4; ++it)
      async_cp16(Bb + (size_t)srow[it] * K + k0 + sgcb[it] * 8,
                 &Bs[it * 2048 + ldsbase]);
    __syncthreads();
#pragma unroll
    for (int kk = 0; kk < 2; ++kk) {
      bf16x8 a[4], b[4];
#pragma unroll
      for (int i = 0; i < 4; ++i) {
        int rr = wm * 64 + i * 16 + m16;
        int cb = (kk << 2) + quad;
        a[i] = *reinterpret_cast<const bf16x8*>(
            &As[rr * BK + ((cb ^ (rr & 7)) << 3)]);
      }
#pragma unroll
      for (int j = 0; j < 4; ++j) {
        int rr = wn * 64 + j * 16 + m16;
        int cb = (kk << 2) + quad;
        b[j] = *reinterpret_cast<const bf16x8*>(
            &Bs[rr * BK + ((cb ^ (rr & 7)) << 3)]);
      }
#pragma unroll
      for (int i = 0; i < 4; ++i)
#pragma unroll
        for (int j = 0; j < 4; ++j)
          acc[i][j] =
              __builtin_amdgcn_mfma_f32_16x16x32_bf16(a[i], b[j], acc[i][j], 0, 0, 0);
    }
  }

  int rowB = tm * BM + wm * 64;
  int colB = tn * BN + wn * 64;
  if (splitk == 1) {
#pragma unroll
    for (int i = 0; i < 4; ++i)
#pragma unroll
      for (int j = 0; j < 4; ++j) {
        int col = colB + j * 16 + m16;
        int row0 = rowB + i * 16 + quad * 4;
#pragma unroll
        for (int t = 0; t < 4; ++t)
          C[(size_t)(row0 + t) * N + col] = acc[i][j][t];
      }
  } else {
#pragma unroll
    for (int i = 0; i < 4; ++i)
#pragma unroll
      for (int j = 0; j < 4; ++j) {
        int col = colB + j * 16 + m16;
        int row0 = rowB + i * 16 + quad * 4;
#pragma unroll
        for (int t = 0; t < 4; ++t)
          atomicAdd(&C[(size_t)(row0 + t) * N + col], acc[i][j][t]);
      }
  }
}

// ------------- direct (no-LDS) BT-GEMM for skinny N (x_proj) -------------
__global__ __launch_bounds__(256) void gemm_bt(
    const unsigned short* __restrict__ A,
    const unsigned short* __restrict__ B,
    float* __restrict__ C,
    int M, int N, int K, int tilesN, int splitk) {
  int bid = blockIdx.x;
  int groupSize = 8 * tilesN;
  int g = bid / groupSize, r = bid % groupSize;
  int tm = g * 8 + (r & 7);
  int tn = r >> 3;

  int Kslice = K / splitk;
  int k_begin = blockIdx.y * Kslice;
  int k_end = k_begin + Kslice;

  int tid = threadIdx.x;
  int wave = tid >> 6, lane = tid & 63;
  int wm = wave & 1, wn = wave >> 1;
  int m16 = lane & 15, quad = lane >> 4;
  int rowBase = tm * 64 + wm * 32;
  int colBase = tn * 128 + wn * 64;

  const unsigned short* a0p = A + (size_t)(rowBase + m16) * K + quad * 8;
  const unsigned short* a1p = A + (size_t)(rowBase + 16 + m16) * K + quad * 8;
  const unsigned short* bp[4];
  bool bok[4];
#pragma unroll
  for (int j = 0; j < 4; ++j) {
    int col = colBase + j * 16 + m16;
    bok[j] = (col < N);
    bp[j] = B + (size_t)(bok[j] ? col : 0) * K + quad * 8;
  }

  f32x4 acc[2][4];
#pragma unroll
  for (int i = 0; i < 2; ++i)
#pragma unroll
    for (int j = 0; j < 4; ++j)
#pragma unroll
      for (int t = 0; t < 4; ++t) acc[i][j][t] = 0.0f;

  bf16x8 zero8;
#pragma unroll
  for (int t = 0; t < 8; ++t) zero8[t] = (__bf16)0.0f;

  for (int k = k_begin; k < k_end; k += 32) {
    bf16x8 a0 = *reinterpret_cast<const bf16x8*>(a0p + k);
    bf16x8 a1 = *reinterpret_cast<const bf16x8*>(a1p + k);
    bf16x8 b[4];
#pragma unroll
    for (int j = 0; j < 4; ++j)
      b[j] = bok[j] ? *reinterpret_cast<const bf16x8*>(bp[j] + k) : zero8;
#pragma unroll
    for (int j = 0; j < 4; ++j) {
      acc[0][j] = __builtin_amdgcn_mfma_f32_16x16x32_bf16(a0, b[j], acc[0][j], 0, 0, 0);
      acc[1][j] = __builtin_amdgcn_mfma_f32_16x16x32_bf16(a1, b[j], acc[1][j], 0, 0, 0);
    }
  }

#pragma unroll
  for (int i = 0; i < 2; ++i)
#pragma unroll
    for (int j = 0; j < 4; ++j) {
      int col = colBase + j * 16 + m16;
      if (col >= N) continue;
      int row0 = rowBase + i * 16 + quad * 4;
      if (splitk == 1) {
#pragma unroll
        for (int t = 0; t < 4; ++t)
          C[(size_t)(row0 + t) * N + col] = acc[i][j][t];
      } else {
#pragma unroll
        for (int t = 0; t < 4; ++t)
          atomicAdd(&C[(size_t)(row0 + t) * N + col], acc[i][j][t]);
      }
    }
}

// ------- depthwise causal conv (K=4) + bias + silu, register window -------
// thread = channel e; 16 timesteps per block row; each proj element read once.
__global__ __launch_bounds__(256) void conv_silu_k(
    const float* __restrict__ proj, const float* __restrict__ cw,
    const float* __restrict__ cb, unsigned short* __restrict__ hb) {
  int e = blockIdx.x * 256 + threadIdx.x;
  int l0 = blockIdx.y * 16;
  float w0 = cw[e * 4 + 0], w1 = cw[e * 4 + 1];
  float w2 = cw[e * 4 + 2], w3 = cw[e * 4 + 3];
  float bias = cb[e];
  float xm3 = (l0 >= 3) ? proj[(size_t)(l0 - 3) * (2 * EE) + e] : 0.0f;
  float xm2 = (l0 >= 2) ? proj[(size_t)(l0 - 2) * (2 * EE) + e] : 0.0f;
  float xm1 = (l0 >= 1) ? proj[(size_t)(l0 - 1) * (2 * EE) + e] : 0.0f;
#pragma unroll
  for (int t = 0; t < 16; ++t) {
    int l = l0 + t;
    float x0 = proj[(size_t)l * (2 * EE) + e];
    float acc = bias + w0 * xm3 + w1 * xm2 + w2 * xm1 + w3 * x0;
    float s = acc / (1.0f + __expf(-acc));
    hb[(size_t)l * EE + e] = f2bf(s);
    xm3 = xm2; xm2 = xm1; xm1 = x0;
  }
}

// ---------------- extract dt rows of ssm -> bf16 [L,128] ----------------
__global__ void dtcast_k(const float* __restrict__ ssm,
                         unsigned short* __restrict__ dtin, int n) {
  int i = blockIdx.x * blockDim.x + threadIdx.x;
  if (i >= n) return;
  int l = i >> 7, r = i & 127;
  dtin[i] = f2bf(ssm[l * 160 + r]);
}

// ---------------- bias + softplus, in place on dt_raw [L,E] ----------------
__global__ void softplus_k(float* __restrict__ dt, const float* __restrict__ db,
                           int n) {
  int i = blockIdx.x * blockDim.x + threadIdx.x;
  if (i >= n) return;
  float x = dt[i] + db[i & (EE - 1)];
  dt[i] = (x > 20.0f) ? x : log1pf(__expf(x));
}

// ================= chunked selective scan (16 states per thread) ===========
__global__ __launch_bounds__(256) void scan_partA(
    const float* __restrict__ dt, const unsigned short* __restrict__ hb,
    const float* __restrict__ ssm, const float* __restrict__ A_log,
    float* __restrict__ P, float* __restrict__ S) {
  int e = blockIdx.y * 256 + threadIdx.x;
  int c = blockIdx.x;
  float Aa[16];
#pragma unroll
  for (int q = 0; q < 4; ++q) {
    float4 a = reinterpret_cast<const float4*>(&A_log[(size_t)e * NS])[q];
    Aa[q * 4 + 0] = -__expf(a.x);
    Aa[q * 4 + 1] = -__expf(a.y);
    Aa[q * 4 + 2] = -__expf(a.z);
    Aa[q * 4 + 3] = -__expf(a.w);
  }
  float s[16], p[16];
#pragma unroll
  for (int n = 0; n < 16; ++n) { s[n] = 0.0f; p[n] = 1.0f; }
  int l0 = c * CT;
#pragma unroll 2
  for (int t = 0; t < CT; ++t) {
    int l = l0 + t;
    size_t o = (size_t)l * EE + e;
    float dtv = dt[o];
    float hv = bf2f(hb[o]);
    float Bv[16];
#pragma unroll
    for (int q = 0; q < 4; ++q)
      *reinterpret_cast<float4*>(&Bv[q * 4]) =
          reinterpret_cast<const float4*>(&ssm[(size_t)l * 160 + 128])[q];
    float z = dtv * hv;
#pragma unroll
    for (int n = 0; n < 16; ++n) {
      float dA = __expf(dtv * Aa[n]);
      s[n] = s[n] * dA + z * Bv[n];
      p[n] *= dA;
    }
  }
  size_t base = ((size_t)c * EE + e) * NS;
#pragma unroll
  for (int q = 0; q < 4; ++q) {
    reinterpret_cast<float4*>(&P[base])[q] = *reinterpret_cast<float4*>(&p[q * 4]);
    reinterpret_cast<float4*>(&S[base])[q] = *reinterpret_cast<float4*>(&s[q * 4]);
  }
}

__global__ __launch_bounds__(256) void scan_chunkB(
    const float* __restrict__ P, float* __restrict__ S) {
  int gidx = blockIdx.x * 256 + threadIdx.x;
  float s = 0.0f;
  float pv = P[gidx], sv = S[gidx];
  for (int c = 0; c < NC; ++c) {
    float pn = 0.0f, sn = 0.0f;
    if (c + 1 < NC) {
      size_t i2 = (size_t)(c + 1) * (EE * NS) + gidx;
      pn = P[i2];
      sn = S[i2];
    }
    float s_next = s * pv + sv;
    S[(size_t)c * (EE * NS) + gidx] = s;
    s = s_next;
    pv = pn; sv = sn;
  }
}

__global__ __launch_bounds__(256) void scan_partC(
    const float* __restrict__ dt, const unsigned short* __restrict__ hb,
    const float* __restrict__ ssm, const float* __restrict__ A_log,
    const float* __restrict__ Dp, const float* __restrict__ proj,
    const float* __restrict__ Sinit, unsigned short* __restrict__ yb) {
  int e = blockIdx.y * 256 + threadIdx.x;
  int c = blockIdx.x;
  float Aa[16];
#pragma unroll
  for (int q = 0; q < 4; ++q) {
    float4 a = reinterpret_cast<const float4*>(&A_log[(size_t)e * NS])[q];
    Aa[q * 4 + 0] = -__expf(a.x);
    Aa[q * 4 + 1] = -__expf(a.y);
    Aa[q * 4 + 2] = -__expf(a.z);
    Aa[q * 4 + 3] = -__expf(a.w);
  }
  float Dv = Dp[e];
  float s[16];
  size_t base = ((size_t)c * EE + e) * NS;
#pragma unroll
  for (int q = 0; q < 4; ++q)
    *reinterpret_cast<float4*>(&s[q * 4]) =
        reinterpret_cast<const float4*>(&Sinit[base])[q];
  int l0 = c * CT;
#pragma unroll 2
  for (int t = 0; t < CT; ++t) {
    int l = l0 + t;
    size_t o = (size_t)l * EE + e;
    float dtv = dt[o];
    float hv = bf2f(hb[o]);
    float Bv[16], Cv[16];
#pragma unroll
    for (int q = 0; q < 4; ++q) {
      *reinterpret_cast<float4*>(&Bv[q * 4]) =
          reinterpret_cast<const float4*>(&ssm[(size_t)l * 160 + 128])[q];
      *reinterpret_cast<float4*>(&Cv[q * 4]) =
          reinterpret_cast<const float4*>(&ssm[(size_t)l * 160 + 144])[q];
    }
    float z = dtv * hv;
    float y = 0.0f;
#pragma unroll
    for (int n = 0; n < 16; ++n) {
      float dA = __expf(dtv * Aa[n]);
      s[n] = s[n] * dA + z * Bv[n];
      y += s[n] * Cv[n];
    }
    float gv = proj[(size_t)l * 2 * EE + EE + e];
    float yv = (y + hv * Dv) * (gv / (1.0f + __expf(-gv)));
    yb[o] = f2bf(yv);
  }
}

extern "C" void kernel_launch(void* const* d_in, const int* in_sizes, int n_in,
                              void* d_out, int out_size, void* d_ws, size_t ws_size,
                              hipStream_t stream) {
  const float* hs   = (const float*)d_in[0];
  const float* w1   = (const float*)d_in[1];
  const float* cw   = (const float*)d_in[2];
  const float* cb   = (const float*)d_in[3];
  const float* xw   = (const float*)d_in[4];
  const float* dtw  = (const float*)d_in[5];
  const float* dtb  = (const float*)d_in[6];
  const float* Alog = (const float*)d_in[7];
  const float* Dp   = (const float*)d_in[8];
  const float* ow   = (const float*)d_in[9];
  float* out = (float*)d_out;

  char* ws = (char*)d_ws;
  size_t off = 0;
  auto alloc = [&](size_t b) {
    char* p = ws + off;
    off += (b + 255) & ~(size_t)255;
    return p;
  };
  float* proj = (float*)alloc((size_t)LL * 2 * EE * 4);
  unsigned short* hb = (unsigned short*)alloc((size_t)LL * EE * 2);
  float* dtf  = (float*)alloc((size_t)LL * EE * 4);
  unsigned short* w1b = (unsigned short*)dtf;  // aliased: dead before dtf written
  unsigned short* hsb = (unsigned short*)alloc((size_t)LL * HH * 2);
  unsigned short* yb  = (unsigned short*)alloc((size_t)LL * EE * 2);
  unsigned short* owb = (unsigned short*)alloc((size_t)HH * EE * 2);
  unsigned short* xwb = (unsigned short*)alloc((size_t)160 * EE * 2);
  float* ssm = (float*)alloc((size_t)LL * 160 * 4);
  unsigned short* dtin = (unsigned short*)alloc((size_t)LL * RR * 2);
  unsigned short* dtwb = (unsigned short*)alloc((size_t)EE * RR * 2);
  float* Pbuf = (float*)alloc((size_t)NC * EE * NS * 4);
  float* Sbuf = (float*)alloc((size_t)NC * EE * NS * 4);

  auto cast = [&](const float* in, unsigned short* o, int nelem) {
    int n4 = nelem / 4;
    cast_bf16_k<<<(n4 + 255) / 256, 256, 0, stream>>>(in, o, n4);
  };
  cast(hs, hsb, LL * HH);
  cast(w1, w1b, 2 * EE * HH);
  cast(xw, xwb, 160 * EE);
  cast(dtw, dtwb, EE * RR);
  cast(ow, owb, HH * EE);
  // zero accumulation targets for split-K atomics
  zero_k<<<(LL * 160 / 4 + 255) / 256, 256, 0, stream>>>(ssm, LL * 160 / 4);
  zero_k<<<(LL * HH / 4 + 255) / 256, 256, 0, stream>>>(out, LL * HH / 4);

  auto gemmL = [&](const unsigned short* A, const unsigned short* Bm, float* Cm,
                   int M, int N, int K, int splitk) {
    int tilesN = N / BN, tilesM = M / BM;
    gemm_lds<<<dim3(tilesM * tilesN, splitk), 256, 0, stream>>>(
        A, Bm, Cm, M, N, K, tilesM, splitk);
  };

  // 1) proj = hs @ in_proj_w^T   [2048, 8192] k=2048
  gemmL(hsb, w1b, proj, LL, 2 * EE, HH, 1);
  // 2) causal depthwise conv + silu -> h (bf16)
  conv_silu_k<<<dim3(EE / 256, LL / 16), 256, 0, stream>>>(proj, cw, cb, hb);
  // 3) ssm = h @ x_proj_w^T   [2048, 160] k=4096, split-K=8 (skinny N)
  {
    int tilesN = (160 + 127) / 128, tilesM = LL / 64;
    gemm_bt<<<dim3(tilesM * tilesN, 8), 256, 0, stream>>>(
        hb, xwb, ssm, LL, 160, EE, tilesN, 8);
  }
  // 4) dt input slice -> bf16
  dtcast_k<<<(LL * RR + 255) / 256, 256, 0, stream>>>(ssm, dtin, LL * RR);
  // 5) dt_raw = dtin @ dt_proj_w^T   [2048, 4096] k=128
  gemmL(dtin, dtwb, dtf, LL, EE, RR, 1);
  // 6) dt = softplus(dt_raw + b)
  softplus_k<<<(LL * EE + 255) / 256, 256, 0, stream>>>(dtf, dtb, LL * EE);
  // 7) chunked selective scan + gating -> y (bf16)
  scan_partA<<<dim3(NC, EE / 256), 256, 0, stream>>>(dtf, hb, ssm, Alog, Pbuf, Sbuf);
  scan_chunkB<<<EE * NS / 256, 256, 0, stream>>>(Pbuf, Sbuf);
  scan_partC<<<dim3(NC, EE / 256), 256, 0, stream>>>(dtf, hb, ssm, Alog, Dp, proj,
                                                     Sbuf, yb);
  // 8) out = y @ out_proj_w^T   [2048, 2048] k=4096, split-K=2 for occupancy
  gemmL(yb, owb, out, LL, HH, EE, 2);
}